// Round 7
// baseline (284.907 us; speedup 1.0000x reference)
//
#include <hip/hip_runtime.h>
#include <hip/hip_bf16.h>

typedef unsigned short ushort_t;
typedef unsigned int uint_t;
typedef __attribute__((ext_vector_type(8))) short short8;
typedef __attribute__((ext_vector_type(4))) float float4v;
typedef __attribute__((ext_vector_type(4))) uint_t uint4v;

#define NLAT 2048
#define DLAT 64

// d_ws layout (ushort units): [0..127] flag area (int at byte 0), then packed weights
#define PW_BASE 128
#define PW0_OFF 0        // layer0: KT=7 -> 7*16*64*8 = 57344 ushorts
#define PW1_OFF 57344    // KT=8 -> 65536 each
#define PW2_OFF 122880
#define PW3_OFF 188416

__device__ __forceinline__ float b2f(ushort_t u) {
  union { uint_t i; float f; } v; v.i = ((uint_t)u) << 16; return v.f;
}
__device__ __forceinline__ ushort_t f2b(float f) {
  uint_t x = __float_as_uint(f);
  uint_t r = (x + 0x7fffu + ((x >> 16) & 1u)) >> 16;   // RNE
  return (ushort_t)r;
}
// HW packed f32x2 -> bf16x2 (v_cvt_pk_bf16_f32)
__device__ __forceinline__ uint_t pack2(float lo, float hi) {
  float2 t; t.x = lo; t.y = hi;
  union { __hip_bfloat162 h; uint_t u; } cv;
  cv.h = __float22bfloat162_rn(t);
  return cv.u;
}
__device__ __forceinline__ int imin(int a, int b) { return a < b ? a : b; }
__device__ __forceinline__ int imax(int a, int b) { return a > b ? a : b; }

__device__ __forceinline__ float ldv(const float* p, long i)    { return p[i]; }
__device__ __forceinline__ float ldv(const ushort_t* p, long i) { return b2f(p[i]); }
__device__ __forceinline__ void stv(float* p, long i, float v)    { p[i] = v; }
__device__ __forceinline__ void stv(ushort_t* p, long i, float v) { p[i] = f2b(v); }

__device__ __forceinline__ float4 load4f(const float* p) { return *(const float4*)p; }
__device__ __forceinline__ float4 load4f(const ushort_t* p) {
  uint2 u = *(const uint2*)p;
  float4 r;
  r.x = b2f((ushort_t)(u.x & 0xffffu)); r.y = b2f((ushort_t)(u.x >> 16));
  r.z = b2f((ushort_t)(u.y & 0xffffu)); r.w = b2f((ushort_t)(u.y >> 16));
  return r;
}

// --- forced-schedule primitives ---------------------------------------------
__device__ __forceinline__ void aload(short8& dst, const ushort_t* a) {
  asm volatile("global_load_dwordx4 %0, %1, off" : "=v"(dst) : "v"(a));
}
template <int N>
__device__ __forceinline__ void vmwait() {
  if constexpr (N == 0)      asm volatile("s_waitcnt vmcnt(0)" ::: "memory");
  else if constexpr (N == 4) asm volatile("s_waitcnt vmcnt(4)" ::: "memory");
  else                       asm volatile("s_waitcnt vmcnt(8)" ::: "memory");
  __builtin_amdgcn_sched_barrier(0);   // rule #18: no MFMA hoist past the wait
}

// ---------------------------------------------------------------------------
// Runtime dtype probe: flag=1 -> fp32 inputs, flag=0 -> bf16
// ---------------------------------------------------------------------------
__global__ void detect_mode(const ushort_t* __restrict__ lat, int* __restrict__ flag) {
  if (threadIdx.x == 0) *flag = 0;
  __syncthreads();
  int big = 0;
  for (int i = threadIdx.x; i < 1024; i += 64) {
    float v = b2f(lat[i]);
    if (!(fabsf(v) < 1e5f)) big = 1;
  }
  if (__any(big) && threadIdx.x == 0) *flag = 1;
}

// ---------------------------------------------------------------------------
// Pack weights as MFMA A-fragments (A = W^T, m = chan_out), sigma k-permuted:
//   element j of frag(mt,kt,lane) = W[sigma][mt*16 + (lane&15)]
//   sigma = 32*kt + 16*(j>>2) + 4*(lane>>4) + (j&3)
// Layer 0: sigma indexes [sampled(192) | coord | pe(12) | pad->224].
// (unchanged — proven verbatim since R0)
// ---------------------------------------------------------------------------
template <typename TI>
__global__ void pack_w_t(const TI* __restrict__ W0, const TI* __restrict__ W1,
                         const TI* __restrict__ W2, const TI* __restrict__ W3,
                         ushort_t* __restrict__ pw, const int* __restrict__ flag, int want)
{
  if (*flag != want) return;
  int g = blockIdx.x * blockDim.x + threadIdx.x;
  if (g >= 31 * 1024) return;
  int lane = g & 63, q = lane >> 4;
  int mt   = (g >> 6) & 15;
  int ktg  = g >> 10;                       // 0..30
  const TI* W; ushort_t* dst; int kt, KT; bool isw0 = false;
  if (ktg < 7)       { W = W0; dst = pw + PW0_OFF; kt = ktg;      KT = 7; isw0 = true; }
  else if (ktg < 15) { W = W1; dst = pw + PW1_OFF; kt = ktg - 7;  KT = 8; }
  else if (ktg < 23) { W = W2; dst = pw + PW2_OFF; kt = ktg - 15; KT = 8; }
  else               { W = W3; dst = pw + PW3_OFF; kt = ktg - 23; KT = 8; }
  int col = mt * 16 + (lane & 15);
  uint_t words[4];
#pragma unroll
  for (int h = 0; h < 4; ++h) {
    ushort_t vv[2];
#pragma unroll
    for (int e = 0; e < 2; ++e) {
      int j = 2 * h + e;
      int f = 32 * kt + 16 * (j >> 2) + 4 * q + (j & 3);
      int row = f;
      if (isw0) row = (f < 192) ? (13 + f) : (f == 192 ? 0 : (f <= 204 ? f - 192 : -1));
      vv[e] = (row >= 0) ? f2b(ldv(W, (long)row * 256 + col)) : (ushort_t)0;
    }
    words[h] = (uint_t)vv[0] | ((uint_t)vv[1] << 16);
  }
  uint4 o; o.x = words[0]; o.y = words[1]; o.z = words[2]; o.w = words[3];
  *(uint4*)(dst + ((size_t)(mt * KT + kt) * 64 + lane) * 8) = o;
}

// ---------------------------------------------------------------------------
// R7: PHASE-STRUCTURED BLOCK (T3 port). R0-R6 all plateaued at the documented
// m97-class ceiling (~800-845 TF, 35% MfmaUtil); single levers (counted vmcnt
// R6, dbuf R3, occupancy R2) are null per m131-m141/m233. The proven fix is
// the 8-phase barrier-paced structure: ONE 512-thread block (8 waves) per CU;
// wave (c,g) owns chans [64c,64c+64) x pt-tiles [4g,4g+4). Per layer, 4
// phases of 2 kt; per phase:
//   { 8x ds_read_b128 (B, this phase) ; 8x asm global_load (A, phase+1) }
//   s_barrier ; lgkmcnt(0) ; vmcnt(just-issued) ; sched_barrier
//   setprio(1) ; 32x MFMA ; setprio(0) ; s_barrier
// Counted vmcnt is never 0 mid-stream; the A-loads for the next layer's
// phase 0 are issued in phase 3 and CROSS the convert barrier in flight.
// Ring slot: consume Ar[p&1], fill Ar[(p+1)&1] — uniform across layers
// (4 phases = even). Convert is IN-PLACE (all act reads retire at the
// layer's last barrier). All register indices compile-time.
// ---------------------------------------------------------------------------
template <int KT>
__device__ __forceinline__ void issueA_ph(const ushort_t* __restrict__ pwl,
                                          short8 (&dst)[8], int ktb, int nk,
                                          int lane, int c)
{
  const ushort_t* abase = pwl + (((size_t)(4 * c) * KT) * 64 + lane) * 8;
#pragma unroll
  for (int kk = 0; kk < 2; ++kk) {
    if (kk < nk) {
#pragma unroll
      for (int m = 0; m < 4; ++m)
        aload(dst[kk * 4 + m], abase + (size_t)(m * KT + ktb + kk) * 512);
    }
  }
}

template <int KT, int NEXTKT>
__device__ __forceinline__ void run_layer_ph(const ushort_t* __restrict__ pwl,
                                             const ushort_t* __restrict__ pwl_next,
                                             float4v (&acc)[4][4],
                                             const ushort_t* __restrict__ act,
                                             int lane, int c, int g,
                                             short8 (&Ar)[2][8])
{
#pragma unroll
  for (int m = 0; m < 4; ++m)
#pragma unroll
    for (int i = 0; i < 4; ++i)
      acc[m][i] = (float4v){0.f, 0.f, 0.f, 0.f};

  int boff[4];
#pragma unroll
  for (int i = 0; i < 4; ++i) boff[i] = ((4 * g + i) << 12) + (lane << 3);

#pragma unroll
  for (int p = 0; p < 4; ++p) {
    const int ktb = 2 * p;
    const int nk  = (KT - ktb >= 2) ? 2 : 1;          // KT=7: phase3 has 1 kt
    // ---- B ds_reads for this phase (conflict-free, linear) ----
    short8 B[2][4];
#pragma unroll
    for (int kk = 0; kk < 2; ++kk)
      if (kk < nk)
#pragma unroll
        for (int i = 0; i < 4; ++i)
          B[kk][i] = *(const short8*)&act[boff[i] + (ktb + kk) * 512];
    // ---- A issue for next phase (or next layer's phase 0) ----
    const int ktb2 = ktb + 2;
    const int nk2  = (p < 3) ? ((KT - ktb2 >= 2) ? 2 : ((KT - ktb2 == 1) ? 1 : 0)) : 0;
    if (p < 3) {
      issueA_ph<KT>(pwl, Ar[(p + 1) & 1], ktb2, nk2, lane, c);
    } else if constexpr (NEXTKT > 0) {
      issueA_ph<NEXTKT>(pwl_next, Ar[0], 0, 2, lane, c);
    }
    // ---- phase barrier + counted waits ----
    __builtin_amdgcn_s_barrier();
    asm volatile("s_waitcnt lgkmcnt(0)" ::: "memory");
    const int justN = (p < 3) ? 4 * nk2 : (NEXTKT > 0 ? 8 : 0);
    if (justN == 8)      vmwait<8>();
    else if (justN == 4) vmwait<4>();
    else                 vmwait<0>();
    // ---- MFMA cluster on slot p&1 ----
    __builtin_amdgcn_s_setprio(1);
#pragma unroll
    for (int kk = 0; kk < 2; ++kk) {
      if (kk < nk) {
        short8 (&Ac)[8] = Ar[p & 1];
#pragma unroll
        for (int i = 0; i < 4; ++i) {
          acc[0][i] = __builtin_amdgcn_mfma_f32_16x16x32_bf16(Ac[kk * 4 + 0], B[kk][i], acc[0][i], 0, 0, 0);
          acc[1][i] = __builtin_amdgcn_mfma_f32_16x16x32_bf16(Ac[kk * 4 + 1], B[kk][i], acc[1][i], 0, 0, 0);
          acc[2][i] = __builtin_amdgcn_mfma_f32_16x16x32_bf16(Ac[kk * 4 + 2], B[kk][i], acc[2][i], 0, 0, 0);
          acc[3][i] = __builtin_amdgcn_mfma_f32_16x16x32_bf16(Ac[kk * 4 + 3], B[kk][i], acc[3][i], 0, 0, 0);
        }
      }
    }
    __builtin_amdgcn_s_setprio(0);
    __builtin_amdgcn_s_barrier();
  }
}

// acc -> bias+relu+bf16 -> act IN PLACE (all reads retired at last barrier).
// Wave (c,g): kt_dst = 2c + (m>>1), half = m&1, tile = 4g+i, lane slot = own
// lane (the proven mapping, c substituted for wv). lgkmcnt(0)+barrier after.
__device__ __forceinline__ void convert_store_ip(float4v (&acc)[4][4],
                                                 ushort_t* __restrict__ act,
                                                 const float* __restrict__ bwl,
                                                 int lane, int c, int g, int q)
{
#pragma unroll
  for (int p2 = 0; p2 < 2; ++p2) {
    const float4 bE = *(const float4*)&bwl[c * 64 + p2 * 32 + 4 * q];
    const float4 bO = *(const float4*)&bwl[c * 64 + p2 * 32 + 16 + 4 * q];
    const int kt = 2 * c + p2;
#pragma unroll
    for (int i = 0; i < 4; ++i) {
      const int t = 4 * g + i;
      const float4v& aE = acc[2 * p2][i];
      const float4v& aO = acc[2 * p2 + 1][i];
      uint4 o;
      o.x = pack2(fmaxf(aE[0] + bE.x, 0.f), fmaxf(aE[1] + bE.y, 0.f));
      o.y = pack2(fmaxf(aE[2] + bE.z, 0.f), fmaxf(aE[3] + bE.w, 0.f));
      o.z = pack2(fmaxf(aO[0] + bO.x, 0.f), fmaxf(aO[1] + bO.y, 0.f));
      o.w = pack2(fmaxf(aO[2] + bO.z, 0.f), fmaxf(aO[3] + bO.w, 0.f));
      *(uint4*)&act[((size_t)t << 12) + kt * 512 + (lane << 3)] = o;
    }
  }
  asm volatile("s_waitcnt lgkmcnt(0)" ::: "memory");
  __builtin_amdgcn_s_barrier();          // writes visible; A-loads stay in flight
}

// ---------------------------------------------------------------------------
// Fused kernel. 512 threads = 8 waves, 128 points/block, grid 2048.
// LDS ~70.8 KB, 1 block/CU; launch_bounds(512,2) caps VGPR at 256
// (acc 64 + A-ring 64 + B 32 + misc ~ 200, 2 waves/SIMD).
// ---------------------------------------------------------------------------
template <typename TI>
__global__ __launch_bounds__(512, 2) void lisa_fused_t(
    const TI* __restrict__ coord, const TI* __restrict__ latent,
    const TI* __restrict__ bias0, const TI* __restrict__ bias1,
    const TI* __restrict__ bias2, const TI* __restrict__ bias3,
    const TI* __restrict__ W4,    const TI* __restrict__ b4,
    const ushort_t* __restrict__ pw, TI* __restrict__ out,
    const int* __restrict__ flag, int want)
{
  if (*flag != want) return;
  __shared__ __align__(16) ushort_t act[8 * 8 * 64 * 8];   // 64 KB, 8 pt-tiles
  __shared__ __align__(16) float bw[4 * 256 + 256 + 1];    // biases | w4 | b4

  const int tid  = threadIdx.x;
  const int lane = tid & 63, q = lane >> 4, m15 = lane & 15;
  const int wv   = tid >> 6;                 // 0..7
  const int c    = wv >> 1;                  // chan-group 0..3 (mt 4c..4c+3)
  const int g    = wv & 1;                   // pt-group 0..1 (tiles 4g..4g+3)
  const long pbase = (long)blockIdx.x * 128 + wv * 16 + m15;

  // ---- bias/w4 table ----
  for (int i = tid; i < 1281; i += 512) {
    float v;
    if (i < 256)       v = ldv(bias0, i);
    else if (i < 512)  v = ldv(bias1, i - 256);
    else if (i < 768)  v = ldv(bias2, i - 512);
    else if (i < 1024) v = ldv(bias3, i - 768);
    else if (i < 1280) v = ldv(W4, i - 1024);
    else               v = ldv(b4, 0);
    bw[i] = v;
  }

  // ---- feature build into sigma-ordered B-frags; thread owns 1 pt,
  //      wave wv owns pt-tile wv (0..7) ----
  {
    const long p = pbase;
    float cd  = ldv(coord, p);
    float ixv = cd * 2048.0f - 0.5f;
    float x0f = floorf(ixv);
    float t   = ixv - x0f;
    int   x0  = (int)x0f;
    int   i0  = imin(imax(x0, 0), NLAT - 1);
    int   i1  = imin(imax(x0 + 1, 0), NLAT - 1);
    float w0 = 1.0f - t, w1 = t;
    int rows0[3] = { imax(i0 - 1, 0), i0, imin(i0 + 1, NLAT - 1) };
    int rows1[3] = { imax(i1 - 1, 0), i1, imin(i1 + 1, NLAT - 1) };
    const TI* lat = latent + (size_t)(p >> 15) * (NLAT * DLAT);
    uint4v hu[7];
#pragma unroll
    for (int tb = 0; tb < 12; ++tb) {
      int region = tb >> 2;
      int d0 = 16 * (tb & 3) + 4 * q;
      float4 a = load4f(lat + (long)rows0[region] * DLAT + d0);
      float4 b = load4f(lat + (long)rows1[region] * DLAT + d0);
      hu[tb >> 1][(tb & 1) * 2 + 0] = pack2(w0 * a.x + w1 * b.x, w0 * a.y + w1 * b.y);
      hu[tb >> 1][(tb & 1) * 2 + 1] = pack2(w0 * a.z + w1 * b.z, w0 * a.w + w1 * b.w);
    }
    float pv[4];
#pragma unroll
    for (int s = 0; s < 4; ++s) {
      int f = 192 + 4 * q + s;
      float v = 0.0f;
      if (f == 192) v = cd;
      else if (f <= 204) {
        int i = f - 193;
        float fr = (float)(1 << (i >> 1));
        float ang = cd * fr;
        v = (i & 1) ? __cosf(ang) : __sinf(ang);
      }
      pv[s] = v;
    }
    hu[6][0] = pack2(pv[0], pv[1]);
    hu[6][1] = pack2(pv[2], pv[3]);
    hu[6][2] = 0; hu[6][3] = 0;

#pragma unroll
    for (int kt = 0; kt < 7; ++kt)
      *(uint4v*)&act[((size_t)wv << 12) + kt * 512 + (lane << 3)] = hu[kt];
  }
  __syncthreads();   // features + bw ready; vmcnt drained -> clean count

  // ---- prologue: issue L0 phase0 A-loads (8 in flight) ----
  short8 Ar[2][8];
  issueA_ph<7>(pw + PW0_OFF, Ar[0], 0, 2, lane, c);

  float4v acc[4][4];

  run_layer_ph<7, 8>(pw + PW0_OFF, pw + PW1_OFF, acc, act, lane, c, g, Ar);
  convert_store_ip(acc, act, bw + 0 * 256, lane, c, g, q);
  run_layer_ph<8, 8>(pw + PW1_OFF, pw + PW2_OFF, acc, act, lane, c, g, Ar);
  convert_store_ip(acc, act, bw + 1 * 256, lane, c, g, q);
  run_layer_ph<8, 8>(pw + PW2_OFF, pw + PW3_OFF, acc, act, lane, c, g, Ar);
  convert_store_ip(acc, act, bw + 2 * 256, lane, c, g, q);
  run_layer_ph<8, 0>(pw + PW3_OFF, nullptr,      acc, act, lane, c, g, Ar);
  // last layer ends with vmwait<0> inside phase 3 -> all asm loads retired

  // ---- final: bias3+relu fused with dot against w4 (wave covers 64 chans
  //      of its 4 pt-tiles; cross-c reduction via LDS) ----
  float psum[4] = {0.f, 0.f, 0.f, 0.f};
#pragma unroll
  for (int m = 0; m < 4; ++m) {
    const float4 b3v = *(const float4*)&bw[3 * 256 + c * 64 + m * 16 + 4 * q];
    const float4 w4v = *(const float4*)&bw[1024 + c * 64 + m * 16 + 4 * q];
#pragma unroll
    for (int i = 0; i < 4; ++i) {
      float v;
      v = fmaxf(acc[m][i][0] + b3v.x, 0.f); psum[i] += v * w4v.x;
      v = fmaxf(acc[m][i][1] + b3v.y, 0.f); psum[i] += v * w4v.y;
      v = fmaxf(acc[m][i][2] + b3v.z, 0.f); psum[i] += v * w4v.z;
      v = fmaxf(acc[m][i][3] + b3v.w, 0.f); psum[i] += v * w4v.w;
    }
  }
#pragma unroll
  for (int i = 0; i < 4; ++i) {
    psum[i] += __shfl_xor(psum[i], 16, 64);
    psum[i] += __shfl_xor(psum[i], 32, 64);
  }

  // act is dead (all reads retired at L3's final barrier) -> overlay partials
  float* part = (float*)act;         // part[c][128] per chan-group
  if (lane < 16) {
#pragma unroll
    for (int i = 0; i < 4; ++i)
      part[c * 128 + (4 * g + i) * 16 + lane] = psum[i];
  }
  __syncthreads();
  if (tid < 128) {
    float s = part[tid] + part[128 + tid] + part[256 + tid] + part[384 + tid]
            + bw[1280];
    stv(out, (long)blockIdx.x * 128 + tid, s);
  }
}

extern "C" void kernel_launch(void* const* d_in, const int* in_sizes, int n_in,
                              void* d_out, int out_size, void* d_ws, size_t ws_size,
                              hipStream_t stream) {
  int* flag = (int*)d_ws;
  ushort_t* pw = (ushort_t*)d_ws + PW_BASE;

  detect_mode<<<1, 64, 0, stream>>>((const ushort_t*)d_in[1], flag);

  // fp32-input variant (flag==1)
  pack_w_t<float><<<62, 512, 0, stream>>>(
      (const float*)d_in[2], (const float*)d_in[4], (const float*)d_in[6],
      (const float*)d_in[8], pw, flag, 1);
  lisa_fused_t<float><<<2048, 512, 0, stream>>>(
      (const float*)d_in[0], (const float*)d_in[1],
      (const float*)d_in[3], (const float*)d_in[5], (const float*)d_in[7],
      (const float*)d_in[9], (const float*)d_in[10], (const float*)d_in[11],
      pw, (float*)d_out, flag, 1);

  // bf16-input variant (flag==0)
  pack_w_t<ushort_t><<<62, 512, 0, stream>>>(
      (const ushort_t*)d_in[2], (const ushort_t*)d_in[4], (const ushort_t*)d_in[6],
      (const ushort_t*)d_in[8], pw, flag, 0);
  lisa_fused_t<ushort_t><<<2048, 512, 0, stream>>>(
      (const ushort_t*)d_in[0], (const ushort_t*)d_in[1],
      (const ushort_t*)d_in[3], (const ushort_t*)d_in[5], (const ushort_t*)d_in[7],
      (const ushort_t*)d_in[9], (const ushort_t*)d_in[10], (const ushort_t*)d_in[11],
      pw, (ushort_t*)d_out, flag, 0);
}

// Round 8
// 226.568 us; speedup vs baseline: 1.2575x; 1.2575x over previous
//
#include <hip/hip_runtime.h>
#include <hip/hip_bf16.h>

typedef unsigned short ushort_t;
typedef unsigned int uint_t;
typedef __attribute__((ext_vector_type(8))) short short8;
typedef __attribute__((ext_vector_type(4))) float float4v;
typedef __attribute__((ext_vector_type(4))) uint_t uint4v;

#define NLAT 2048
#define DLAT 64

// d_ws layout (ushort units): [0..127] flag area (int at byte 0), then packed weights
#define PW_BASE 128
#define PW0_OFF 0        // layer0: KT=7 -> 7*16*64*8 = 57344 ushorts
#define PW1_OFF 57344    // KT=8 -> 65536 each
#define PW2_OFF 122880
#define PW3_OFF 188416

__device__ __forceinline__ float b2f(ushort_t u) {
  union { uint_t i; float f; } v; v.i = ((uint_t)u) << 16; return v.f;
}
__device__ __forceinline__ ushort_t f2b(float f) {
  uint_t x = __float_as_uint(f);
  uint_t r = (x + 0x7fffu + ((x >> 16) & 1u)) >> 16;   // RNE
  return (ushort_t)r;
}
__device__ __forceinline__ uint_t pack2(float lo, float hi) {
  float2 t; t.x = lo; t.y = hi;
  union { __hip_bfloat162 h; uint_t u; } cv;
  cv.h = __float22bfloat162_rn(t);
  return cv.u;
}
__device__ __forceinline__ int imin(int a, int b) { return a < b ? a : b; }
__device__ __forceinline__ int imax(int a, int b) { return a > b ? a : b; }

__device__ __forceinline__ float ldv(const float* p, long i)    { return p[i]; }
__device__ __forceinline__ float ldv(const ushort_t* p, long i) { return b2f(p[i]); }
__device__ __forceinline__ void stv(float* p, long i, float v)    { p[i] = v; }
__device__ __forceinline__ void stv(ushort_t* p, long i, float v) { p[i] = f2b(v); }

__device__ __forceinline__ float4 load4f(const float* p) { return *(const float4*)p; }
__device__ __forceinline__ float4 load4f(const ushort_t* p) {
  uint2 u = *(const uint2*)p;
  float4 r;
  r.x = b2f((ushort_t)(u.x & 0xffffu)); r.y = b2f((ushort_t)(u.x >> 16));
  r.z = b2f((ushort_t)(u.y & 0xffffu)); r.w = b2f((ushort_t)(u.y >> 16));
  return r;
}

// --- forced-schedule primitives ---------------------------------------------
// Volatile asm keeps program order among volatile asm; register deps protect
// WAR on ring slots; manual waitcnt + sched_barrier orders consumers.
__device__ __forceinline__ void aload(short8& dst, const ushort_t* a) {
  asm volatile("global_load_dwordx4 %0, %1, off" : "=v"(dst) : "v"(a));
}
__device__ __forceinline__ void dsread(short8& dst, const ushort_t* p) {
  asm volatile("ds_read_b128 %0, %1"
               : "=v"(dst)
               : "v"((const __attribute__((address_space(3))) ushort_t*)p));
}
template <int N>
__device__ __forceinline__ void vmwait() {
  if constexpr (N == 0)       asm volatile("s_waitcnt vmcnt(0)"  ::: "memory");
  else if constexpr (N == 4)  asm volatile("s_waitcnt vmcnt(4)"  ::: "memory");
  else if constexpr (N == 8)  asm volatile("s_waitcnt vmcnt(8)"  ::: "memory");
  else                        asm volatile("s_waitcnt vmcnt(12)" ::: "memory");
}
template <int N>
__device__ __forceinline__ void lgwait() {
  if constexpr (N == 0) asm volatile("s_waitcnt lgkmcnt(0)" ::: "memory");
  else                  asm volatile("s_waitcnt lgkmcnt(4)" ::: "memory");
}

// ---------------------------------------------------------------------------
// Runtime dtype probe: flag=1 -> fp32 inputs, flag=0 -> bf16
// ---------------------------------------------------------------------------
__global__ void detect_mode(const ushort_t* __restrict__ lat, int* __restrict__ flag) {
  if (threadIdx.x == 0) *flag = 0;
  __syncthreads();
  int big = 0;
  for (int i = threadIdx.x; i < 1024; i += 64) {
    float v = b2f(lat[i]);
    if (!(fabsf(v) < 1e5f)) big = 1;
  }
  if (__any(big) && threadIdx.x == 0) *flag = 1;
}

// ---------------------------------------------------------------------------
// Pack weights as MFMA A-fragments (A = W^T, m = chan_out), sigma k-permuted:
//   element j of frag(mt,kt,lane) = W[sigma][mt*16 + (lane&15)]
//   sigma = 32*kt + 16*(j>>2) + 4*(lane>>4) + (j&3)
// Layer 0: sigma indexes [sampled(192) | coord | pe(12) | pad->224].
// Merged: ONE dispatch, runtime dtype branch (block-uniform).
// ---------------------------------------------------------------------------
template <typename TI>
__device__ __forceinline__ void pack_body(const TI* __restrict__ W0, const TI* __restrict__ W1,
                                          const TI* __restrict__ W2, const TI* __restrict__ W3,
                                          ushort_t* __restrict__ pw)
{
  int g = blockIdx.x * blockDim.x + threadIdx.x;
  if (g >= 31 * 1024) return;
  int lane = g & 63, q = lane >> 4;
  int mt   = (g >> 6) & 15;
  int ktg  = g >> 10;                       // 0..30
  const TI* W; ushort_t* dst; int kt, KT; bool isw0 = false;
  if (ktg < 7)       { W = W0; dst = pw + PW0_OFF; kt = ktg;      KT = 7; isw0 = true; }
  else if (ktg < 15) { W = W1; dst = pw + PW1_OFF; kt = ktg - 7;  KT = 8; }
  else if (ktg < 23) { W = W2; dst = pw + PW2_OFF; kt = ktg - 15; KT = 8; }
  else               { W = W3; dst = pw + PW3_OFF; kt = ktg - 23; KT = 8; }
  int col = mt * 16 + (lane & 15);
  uint_t words[4];
#pragma unroll
  for (int h = 0; h < 4; ++h) {
    ushort_t vv[2];
#pragma unroll
    for (int e = 0; e < 2; ++e) {
      int j = 2 * h + e;
      int f = 32 * kt + 16 * (j >> 2) + 4 * q + (j & 3);
      int row = f;
      if (isw0) row = (f < 192) ? (13 + f) : (f == 192 ? 0 : (f <= 204 ? f - 192 : -1));
      vv[e] = (row >= 0) ? f2b(ldv(W, (long)row * 256 + col)) : (ushort_t)0;
    }
    words[h] = (uint_t)vv[0] | ((uint_t)vv[1] << 16);
  }
  uint4 o; o.x = words[0]; o.y = words[1]; o.z = words[2]; o.w = words[3];
  *(uint4*)(dst + ((size_t)(mt * KT + kt) * 64 + lane) * 8) = o;
}

__global__ void pack_w_u(const void* W0, const void* W1, const void* W2, const void* W3,
                         ushort_t* __restrict__ pw, const int* __restrict__ flag)
{
  if (*flag == 1)
    pack_body<float>((const float*)W0, (const float*)W1, (const float*)W2, (const float*)W3, pw);
  else
    pack_body<ushort_t>((const ushort_t*)W0, (const ushort_t*)W1, (const ushort_t*)W2, (const ushort_t*)W3, pw);
}

// ---------------------------------------------------------------------------
// R8: BOTH STREAMS ASM-FORCED. R6 proved the A-ring survives at asm level and
// is null -> the per-kt stall is the B-side: in-loop ds_read -> lgkm wait ->
// MFMA (compiler collapsed every C++ B-prefetch; R5 VGPR evidence). Here B is
// double-buffered via asm ds_read_b128 with counted lgkmcnt(4): B(kt+1) is in
// flight while MFMA runs on B(kt). A-ring deepened to distance 3, vmcnt(12),
// with GLOBAL slot indexing (BASE per layer = 0,3,3,3) so next-layer loads
// cross the convert barrier in flight.
//   per iter kt: dsread x4 (B(kt+1)) ; aload x4 (A(kt+3) / next-layer) ;
//                lgkmcnt(4) ; vmcnt(12) ; sched_barrier ; 16 MFMA (setprio)
// lgkm audit: only our asm DS ops live in-loop (bias reads + act writes are
// in convert, which drains to 0). vmcnt audit: steady 16 in flight after
// issue, wait 12 retires exactly A(kt); tail 8 -> 4 -> 0.
// ---------------------------------------------------------------------------
template <int KT, int BASE, int NEXTKT>
__device__ __forceinline__ void run_layer_fp(const ushort_t* __restrict__ pwl,
                                             const ushort_t* __restrict__ pwl_next,
                                             float4v (&acc)[4][4],
                                             const ushort_t* __restrict__ act,
                                             int lane, int wv, short8 (&Ar)[4][4])
{
#pragma unroll
  for (int m = 0; m < 4; ++m)
#pragma unroll
    for (int i = 0; i < 4; ++i)
      acc[m][i] = (float4v){0.f, 0.f, 0.f, 0.f};

  const ushort_t* abase = pwl + (((size_t)(4 * wv) * KT) * 64 + lane) * 8;
  const ushort_t* nbase = nullptr;
  if constexpr (NEXTKT > 0)
    nbase = pwl_next + (((size_t)(4 * wv) * NEXTKT) * 64 + lane) * 8;

  int boff[4];
#pragma unroll
  for (int i = 0; i < 4; ++i) boff[i] = (((wv + i) & 3) << 12) + (lane << 3);

  short8 B0[4], B1[4];
  // issue B(0) -> slot 0 (4 lgkm items outstanding)
#pragma unroll
  for (int i = 0; i < 4; ++i) dsread(B0[i], act + boff[i]);

#pragma unroll
  for (int kt = 0; kt < KT; ++kt) {
    short8 (&Bc)[4] = (kt & 1) ? B1 : B0;   // compile-time (unrolled)
    short8 (&Bn)[4] = (kt & 1) ? B0 : B1;
    // ---- issue B(kt+1): outstanding 4 -> 8 ----
    if (kt + 1 < KT) {
#pragma unroll
      for (int i = 0; i < 4; ++i) dsread(Bn[i], act + boff[i] + (kt + 1) * 512);
    }
    // ---- issue A(kt+3) into ring slot (BASE+kt+3)&3 ----
    if (kt + 3 < KT) {
#pragma unroll
      for (int m = 0; m < 4; ++m)
        aload(Ar[(BASE + kt + 3) & 3][m], abase + (size_t)(m * KT + kt + 3) * 512);
    } else if constexpr (NEXTKT > 0) {
      const int nk = kt + 3 - KT;           // 0,1,2 (compile-time)
#pragma unroll
      for (int m = 0; m < 4; ++m)
        aload(Ar[(BASE + kt + 3) & 3][m], nbase + (size_t)(m * NEXTKT + nk) * 512);
    }
    // ---- counted waits: retire B(kt) and A(kt), keep the rest in flight ----
    if (kt + 1 < KT) lgwait<4>(); else lgwait<0>();
    if (kt + 3 < KT || NEXTKT > 0) vmwait<12>();
    else if (kt == KT - 3)         vmwait<8>();
    else if (kt == KT - 2)         vmwait<4>();
    else                           vmwait<0>();
    __builtin_amdgcn_sched_barrier(0);      // rule #18: no MFMA hoist past waits
    // ---- MFMA burst on A slot (BASE+kt)&3, B slot kt&1 ----
    short8 (&Ac)[4] = Ar[(BASE + kt) & 3];
    __builtin_amdgcn_s_setprio(1);
#pragma unroll
    for (int i = 0; i < 4; ++i) {
      acc[0][i] = __builtin_amdgcn_mfma_f32_16x16x32_bf16(Ac[0], Bc[i], acc[0][i], 0, 0, 0);
      acc[1][i] = __builtin_amdgcn_mfma_f32_16x16x32_bf16(Ac[1], Bc[i], acc[1][i], 0, 0, 0);
      acc[2][i] = __builtin_amdgcn_mfma_f32_16x16x32_bf16(Ac[2], Bc[i], acc[2][i], 0, 0, 0);
      acc[3][i] = __builtin_amdgcn_mfma_f32_16x16x32_bf16(Ac[3], Bc[i], acc[3][i], 0, 0, 0);
    }
    __builtin_amdgcn_s_setprio(0);
  }
}

// acc -> bias+relu+bf16 -> actN (other act buffer). kt_dst = 2wv + (mt>>1),
// half = mt&1, lane slot = own lane; slot i -> pt p=(wv+i)&3 (address-only).
// Single barrier; lgkmcnt(0) only — the 12 in-flight A-loads cross it.
__device__ __forceinline__ void convert_store(float4v (&acc)[4][4],
                                              ushort_t* __restrict__ actN,
                                              const float* __restrict__ bwl,
                                              int lane, int wv, int q)
{
#pragma unroll
  for (int p2 = 0; p2 < 2; ++p2) {
    const float4 bE = *(const float4*)&bwl[wv * 64 + p2 * 32 + 4 * q];
    const float4 bO = *(const float4*)&bwl[wv * 64 + p2 * 32 + 16 + 4 * q];
    const int kt = 2 * wv + p2;
#pragma unroll
    for (int i = 0; i < 4; ++i) {
      const int p = (wv + i) & 3;
      const float4v& aE = acc[2 * p2][i];
      const float4v& aO = acc[2 * p2 + 1][i];
      uint4 o;
      o.x = pack2(fmaxf(aE[0] + bE.x, 0.f), fmaxf(aE[1] + bE.y, 0.f));
      o.y = pack2(fmaxf(aE[2] + bE.z, 0.f), fmaxf(aE[3] + bE.w, 0.f));
      o.z = pack2(fmaxf(aO[0] + bO.x, 0.f), fmaxf(aO[1] + bO.y, 0.f));
      o.w = pack2(fmaxf(aO[2] + bO.z, 0.f), fmaxf(aO[3] + bO.w, 0.f));
      *(uint4*)&actN[(size_t)(p << 12) + kt * 512 + (lane << 3)] = o;
    }
  }
  asm volatile("s_waitcnt lgkmcnt(0)" ::: "memory");
  __builtin_amdgcn_s_barrier();
}

// ---------------------------------------------------------------------------
// Fused body. 256 threads = 4 waves, 64 points/block, grid 4096.
// LDS ~70.7 KB -> 2 blocks/CU. Arch VGPR ~ ring 64 + B 32 + addrs ~ 140,
// acc 64 in AGPR -> total ~205 <= 256, 2 waves/SIMD, no spill expected.
// ---------------------------------------------------------------------------
template <typename TI>
__device__ __forceinline__ void fused_body(
    const TI* __restrict__ coord, const TI* __restrict__ latent,
    const TI* __restrict__ bias0, const TI* __restrict__ bias1,
    const TI* __restrict__ bias2, const TI* __restrict__ bias3,
    const TI* __restrict__ W4,    const TI* __restrict__ b4,
    const ushort_t* __restrict__ pw, TI* __restrict__ out,
    ushort_t (*act)[4 * 8 * 64 * 8], float* bw)
{
  const int tid  = threadIdx.x;
  const int lane = tid & 63, q = lane >> 4, m15 = lane & 15;
  const int wv   = tid >> 6;                               // 0..3
  const long pbase = (long)blockIdx.x * 64 + wv * 16 + m15;

  // ---- bias/w4 table ----
  for (int i = tid; i < 1281; i += 256) {
    float v;
    if (i < 256)       v = ldv(bias0, i);
    else if (i < 512)  v = ldv(bias1, i - 256);
    else if (i < 768)  v = ldv(bias2, i - 512);
    else if (i < 1024) v = ldv(bias3, i - 768);
    else if (i < 1280) v = ldv(W4, i - 1024);
    else               v = ldv(b4, 0);
    bw[i] = v;
  }

  // ---- feature build into sigma-ordered B-frags; wave wv owns pt-tile wv ----
  {
    const long p = pbase;
    float c   = ldv(coord, p);
    float ixv = c * 2048.0f - 0.5f;
    float x0f = floorf(ixv);
    float t   = ixv - x0f;
    int   x0  = (int)x0f;
    int   i0  = imin(imax(x0, 0), NLAT - 1);
    int   i1  = imin(imax(x0 + 1, 0), NLAT - 1);
    float w0 = 1.0f - t, w1 = t;
    int rows0[3] = { imax(i0 - 1, 0), i0, imin(i0 + 1, NLAT - 1) };
    int rows1[3] = { imax(i1 - 1, 0), i1, imin(i1 + 1, NLAT - 1) };
    const TI* lat = latent + (size_t)(p >> 15) * (NLAT * DLAT);
    uint4v hu[7];
#pragma unroll
    for (int tb = 0; tb < 12; ++tb) {
      int region = tb >> 2;
      int d0 = 16 * (tb & 3) + 4 * q;
      float4 a = load4f(lat + (long)rows0[region] * DLAT + d0);
      float4 b = load4f(lat + (long)rows1[region] * DLAT + d0);
      hu[tb >> 1][(tb & 1) * 2 + 0] = pack2(w0 * a.x + w1 * b.x, w0 * a.y + w1 * b.y);
      hu[tb >> 1][(tb & 1) * 2 + 1] = pack2(w0 * a.z + w1 * b.z, w0 * a.w + w1 * b.w);
    }
    float pv[4];
#pragma unroll
    for (int s = 0; s < 4; ++s) {
      int f = 192 + 4 * q + s;
      float v = 0.0f;
      if (f == 192) v = c;
      else if (f <= 204) {
        int i = f - 193;
        float fr = (float)(1 << (i >> 1));
        float ang = c * fr;
        v = (i & 1) ? __cosf(ang) : __sinf(ang);
      }
      pv[s] = v;
    }
    hu[6][0] = pack2(pv[0], pv[1]);
    hu[6][1] = pack2(pv[2], pv[3]);
    hu[6][2] = 0; hu[6][3] = 0;

#pragma unroll
    for (int kt = 0; kt < 7; ++kt)
      *(uint4v*)&act[0][((size_t)(wv * 8 + kt) * 64 + lane) * 8] = hu[kt];
  }
  __syncthreads();   // features + bw ready; vm/lgkm drained -> clean counts

  // ---- prologue: A(0),A(1),A(2) into ring slots 0,1,2 (12 in flight) ----
  short8 Ar[4][4];
  {
    const ushort_t* abase = pw + PW0_OFF + (((size_t)(4 * wv) * 7) * 64 + lane) * 8;
#pragma unroll
    for (int s = 0; s < 3; ++s)
#pragma unroll
      for (int m = 0; m < 4; ++m)
        aload(Ar[s][m], abase + (size_t)(m * 7 + s) * 512);
  }

  float4v acc[4][4];

  run_layer_fp<7, 0, 8>(pw + PW0_OFF, pw + PW1_OFF, acc, act[0], lane, wv, Ar);
  convert_store(acc, act[1], bw + 0 * 256, lane, wv, q);
  run_layer_fp<8, 3, 8>(pw + PW1_OFF, pw + PW2_OFF, acc, act[1], lane, wv, Ar);
  convert_store(acc, act[0], bw + 1 * 256, lane, wv, q);
  run_layer_fp<8, 3, 8>(pw + PW2_OFF, pw + PW3_OFF, acc, act[0], lane, wv, Ar);
  convert_store(acc, act[1], bw + 2 * 256, lane, wv, q);
  run_layer_fp<8, 3, 0>(pw + PW3_OFF, nullptr,      acc, act[1], lane, wv, Ar);
  // last layer ends with vmwait<0>/lgwait<0> -> all asm ops retired

  // ---- final: bias3+relu fused with dot against w4 ----
  float psum[4] = {0.f, 0.f, 0.f, 0.f};
#pragma unroll
  for (int m = 0; m < 4; ++m) {
    const float4 b3v = *(const float4*)&bw[3 * 256 + wv * 64 + m * 16 + 4 * q];
    const float4 w4v = *(const float4*)&bw[1024 + wv * 64 + m * 16 + 4 * q];
#pragma unroll
    for (int i = 0; i < 4; ++i) {
      float v;
      v = fmaxf(acc[m][i][0] + b3v.x, 0.f); psum[i] += v * w4v.x;
      v = fmaxf(acc[m][i][1] + b3v.y, 0.f); psum[i] += v * w4v.y;
      v = fmaxf(acc[m][i][2] + b3v.z, 0.f); psum[i] += v * w4v.z;
      v = fmaxf(acc[m][i][3] + b3v.w, 0.f); psum[i] += v * w4v.w;
    }
  }
#pragma unroll
  for (int i = 0; i < 4; ++i) {
    psum[i] += __shfl_xor(psum[i], 16, 64);
    psum[i] += __shfl_xor(psum[i], 32, 64);
  }

  asm volatile("" ::: "memory");
  __builtin_amdgcn_s_barrier();   // all act reads retired -> reuse as scratch
  float* part = (float*)act[0];   // [wv][64] partials
  if (lane < 16) {
#pragma unroll
    for (int i = 0; i < 4; ++i) {
      const int p = (wv + i) & 3;
      part[wv * 64 + p * 16 + lane] = psum[i];
    }
  }
  __syncthreads();
  if (tid < 64) {
    float s = part[tid] + part[64 + tid] + part[128 + tid] + part[192 + tid]
            + bw[1280];
    stv(out, (long)blockIdx.x * 64 + tid, s);
  }
}

// Merged kernel: ONE dispatch, block-uniform runtime dtype branch.
__global__ __launch_bounds__(256, 2) void lisa_fused_u(
    const void* coord, const void* latent,
    const void* bias0, const void* bias1, const void* bias2, const void* bias3,
    const void* W4,    const void* b4,
    const ushort_t* __restrict__ pw, void* out, const int* __restrict__ flag)
{
  __shared__ __align__(16) ushort_t act[2][4 * 8 * 64 * 8];  // 2 x 32 KB
  __shared__ __align__(16) float bw[4 * 256 + 256 + 1];

  if (*flag == 1)
    fused_body<float>((const float*)coord, (const float*)latent,
                      (const float*)bias0, (const float*)bias1,
                      (const float*)bias2, (const float*)bias3,
                      (const float*)W4, (const float*)b4,
                      pw, (float*)out, act, bw);
  else
    fused_body<ushort_t>((const ushort_t*)coord, (const ushort_t*)latent,
                         (const ushort_t*)bias0, (const ushort_t*)bias1,
                         (const ushort_t*)bias2, (const ushort_t*)bias3,
                         (const ushort_t*)W4, (const ushort_t*)b4,
                         pw, (ushort_t*)out, act, bw);
}

extern "C" void kernel_launch(void* const* d_in, const int* in_sizes, int n_in,
                              void* d_out, int out_size, void* d_ws, size_t ws_size,
                              hipStream_t stream) {
  int* flag = (int*)d_ws;
  ushort_t* pw = (ushort_t*)d_ws + PW_BASE;

  detect_mode<<<1, 64, 0, stream>>>((const ushort_t*)d_in[1], flag);

  pack_w_u<<<62, 512, 0, stream>>>(d_in[2], d_in[4], d_in[6], d_in[8], pw, flag);

  lisa_fused_u<<<4096, 256, 0, stream>>>(
      d_in[0], d_in[1], d_in[3], d_in[5], d_in[7], d_in[9],
      d_in[10], d_in[11], pw, d_out, flag);
}